// Round 1
// baseline (22617.009 us; speedup 1.0000x reference)
//
#include <hip/hip_runtime.h>

// RNNModel: 2-layer LSTM (B=64,T=400,E=H=500) + MLP head (800->100->2).
// Strategy: persistent kernel, 256 blocks (1/CU), hand-rolled grid barrier.
// Grid-step s computes LSTM1 step s and LSTM2 step s-1 (pipelined): 401 steps.
// f32 FMA in K=125 chunks, chunk sums combined in f64; gates/c in f64.

#define NBLK 256
#define NTHR 512

#define Bn 64
#define Tn 400
#define Hn 500

// ws byte offsets
#define OFF_C1 0            // double [64*500]
#define OFF_C2 262144       // double [64*500]
#define OFF_H1 524288       // float [2][64*500]
#define OFF_H2 786432       // float [2][64*500]
#define OFF_D1 1048576      // float [64*800]
#define OFF_D2 1310720      // float [64*100]
#define OFF_CNT 1572864     // unsigned counter

__device__ __forceinline__ void gbar(unsigned* cnt, unsigned target) {
    __syncthreads();
    if (threadIdx.x == 0) {
        __threadfence();  // flush this block's stores device-wide (cross-XCD)
        unsigned prevv = __hip_atomic_fetch_add(cnt, 1u, __ATOMIC_ACQ_REL,
                                                __HIP_MEMORY_SCOPE_AGENT);
        if (prevv + 1u != target) {
            while (__hip_atomic_load(cnt, __ATOMIC_ACQUIRE,
                                     __HIP_MEMORY_SCOPE_AGENT) < target) {
                __builtin_amdgcn_s_sleep(2);
            }
        }
    }
    __syncthreads();
}

extern "C" __global__ void __launch_bounds__(NTHR)
rnn_all(const int* __restrict__ X, const float* __restrict__ embed,
        const float* __restrict__ k1, const float* __restrict__ b1,
        const float* __restrict__ k2, const float* __restrict__ b2,
        const float* __restrict__ w1, const float* __restrict__ bw1,
        const float* __restrict__ w2, const float* __restrict__ bw2,
        const float* __restrict__ wpm, const float* __restrict__ bpv,
        float* __restrict__ out, char* __restrict__ ws)
{
    __shared__ float s_in[16 * 1020];   // 16 batch rows x 1000 (stride 1020)
    __shared__ int s_rowid[16];
    float* s_comb = s_in;               // aliased after K-loop: [8][4][256]

    double* c1p = (double*)(ws + OFF_C1);
    double* c2p = (double*)(ws + OFF_C2);
    float* h1b = (float*)(ws + OFF_H1);
    float* h2b = (float*)(ws + OFF_H2);
    float* d1p = (float*)(ws + OFF_D1);
    float* d2p = (float*)(ws + OFF_D2);
    unsigned* cnt = (unsigned*)(ws + OFF_CNT);

    const int bid = blockIdx.x;
    const int tid = threadIdx.x;
    const int L = bid >> 7;            // 0: LSTM layer 1, 1: layer 2
    const int btile = (bid >> 5) & 3;  // 4 batch tiles of 16
    const int utile = bid & 31;        // 32 unit tiles of 16 (500 used)
    const int b0 = btile * 16;
    const int ug = tid & 3;            // float4 group within u-tile
    const int bl = (tid >> 2) & 15;    // batch lane within tile
    const int kh = tid >> 6;           // K chunk 0..7 (125 each)
    const int ugc = min(utile * 4 + ug, 124);  // clamp tail (u>=500 masked later)

    const float* W = L ? k2 : k1;      // [1000][2000], gates i,j,f,o
    const float* bias = L ? b2 : b1;
    double* cb = L ? c2p : c1p;

    unsigned ep = 0;

    for (int s = 0; s <= Tn; ++s) {
        const bool active = L ? (s >= 1) : (s < Tn);
        const int cur = s & 1;
        const int prv = cur ^ 1;
        const float* h1prev = h1b + prv * 32000;
        const float* h2prev = h2b + prv * 32000;
        float* hout = (L ? h2b : h1b) + cur * 32000;

        if (active) {
            const int t = L ? (s - 1) : s;
            if (tid < 16) s_rowid[tid] = (L == 0) ? X[(b0 + tid) * Tn + t] : 0;
            __syncthreads();
            // stage input vector [x_part | h_part] for 16 batch rows
            for (int i = tid; i < 2000; i += NTHR) {
                int bi = i / 125;
                int v = i - bi * 125;
                const float4* srcA;
                const float4* srcB;
                if (L == 0) {
                    srcA = (const float4*)(embed + (size_t)s_rowid[bi] * 500) + v;
                    srcB = (const float4*)(h1prev + (b0 + bi) * 500) + v;
                } else {
                    srcA = (const float4*)(h1prev + (b0 + bi) * 500) + v;
                    srcB = (const float4*)(h2prev + (b0 + bi) * 500) + v;
                }
                *(float4*)(s_in + bi * 1020 + 4 * v) = *srcA;
                *(float4*)(s_in + bi * 1020 + 500 + 4 * v) = *srcB;
            }
            __syncthreads();
            // K-loop: 125 iters, 16 f32 FMA each (4 u x 4 gates)
            const float* wp0 = W + (size_t)(kh * 125) * 2000 + ugc * 4;
            const float* inp = s_in + bl * 1020 + kh * 125;
            float4 a0 = {0.f, 0.f, 0.f, 0.f};
            float4 a1 = a0, a2 = a0, a3 = a0;
            #pragma unroll 5
            for (int i = 0; i < 125; ++i) {
                const float x = inp[i];
                const float4 w0 = *(const float4*)(wp0);
                const float4 w1v = *(const float4*)(wp0 + 500);
                const float4 w2v = *(const float4*)(wp0 + 1000);
                const float4 w3v = *(const float4*)(wp0 + 1500);
                a0.x = fmaf(x, w0.x, a0.x);
                a0.y = fmaf(x, w0.y, a0.y);
                a0.z = fmaf(x, w0.z, a0.z);
                a0.w = fmaf(x, w0.w, a0.w);
                a1.x = fmaf(x, w1v.x, a1.x);
                a1.y = fmaf(x, w1v.y, a1.y);
                a1.z = fmaf(x, w1v.z, a1.z);
                a1.w = fmaf(x, w1v.w, a1.w);
                a2.x = fmaf(x, w2v.x, a2.x);
                a2.y = fmaf(x, w2v.y, a2.y);
                a2.z = fmaf(x, w2v.z, a2.z);
                a2.w = fmaf(x, w2v.w, a2.w);
                a3.x = fmaf(x, w3v.x, a3.x);
                a3.y = fmaf(x, w3v.y, a3.y);
                a3.z = fmaf(x, w3v.z, a3.z);
                a3.w = fmaf(x, w3v.w, a3.w);
                wp0 += 2000;
            }
            __syncthreads();   // all in_lds reads done before aliasing as comb
            {
                int cbase = kh * 1024 + bl * 16 + ug * 4;
                *(float4*)&s_comb[cbase] = a0;
                *(float4*)&s_comb[cbase + 256] = a1;
                *(float4*)&s_comb[cbase + 512] = a2;
                *(float4*)&s_comb[cbase + 768] = a3;
            }
            __syncthreads();
            // gate phase: one thread per (b,u) unit, f64 combine + LSTM cell
            if (tid < 256) {
                const int uu = tid & 15;
                const int u = utile * 16 + uu;
                if (u < Hn) {
                    const int b = b0 + (tid >> 4);
                    double zi = 0, zj = 0, zf = 0, zo = 0;
                    #pragma unroll
                    for (int q = 0; q < 8; ++q) {
                        zi += (double)s_comb[q * 1024 + tid];
                        zj += (double)s_comb[q * 1024 + 256 + tid];
                        zf += (double)s_comb[q * 1024 + 512 + tid];
                        zo += (double)s_comb[q * 1024 + 768 + tid];
                    }
                    zi += (double)bias[u];
                    zj += (double)bias[500 + u];
                    zf += (double)bias[1000 + u];
                    zo += (double)bias[1500 + u];
                    double* cc = cb + b * 500 + u;
                    const double cold = *cc;
                    const double gi = 1.0 / (1.0 + exp(-zi));
                    const double gf = 1.0 / (1.0 + exp(-(zf + 1.0)));
                    const double go = 1.0 / (1.0 + exp(-zo));
                    const double cnew = gf * cold + gi * tanh(zj);
                    *cc = cnew;
                    hout[b * 500 + u] = (float)(go * tanh(cnew));
                }
            }
        }
        ++ep;
        gbar(cnt, ep * NBLK);
    }

    // ---- dense head (all f64 accumulation) ----
    const float* last = h2b + (Tn & 1) * 32000;  // h2 at t=399 -> phase 0
    if (tid < 200) {
        int o = bid * 200 + tid;                  // 256*200 = 51200 = 64*800
        int b = o / 800, j = o - b * 800;
        const float* lr = last + b * 500;
        double acc = 0;
        for (int kk = 0; kk < 500; ++kk)
            acc += (double)lr[kk] * (double)w1[(size_t)kk * 800 + j];
        acc += (double)bw1[j];
        d1p[b * 800 + j] = (float)fmax(acc, 0.0);
    }
    ++ep;
    gbar(cnt, ep * NBLK);
    if (tid < 25) {
        int o = bid * 25 + tid;                   // 256*25 = 6400 = 64*100
        int b = o / 100, j = o - b * 100;
        const float* dr = d1p + b * 800;
        double acc = 0;
        for (int kk = 0; kk < 800; ++kk)
            acc += (double)dr[kk] * (double)w2[(size_t)kk * 100 + j];
        acc += (double)bw2[j];
        d2p[b * 100 + j] = (float)fmax(acc, 0.0);
    }
    ++ep;
    gbar(cnt, ep * NBLK);
    if (bid == 0 && tid < 128) {
        int b = tid >> 1, c = tid & 1;
        const float* dr = d2p + b * 100;
        double acc = 0;
        for (int kk = 0; kk < 100; ++kk)
            acc += (double)dr[kk] * (double)wpm[kk * 2 + c];
        acc += (double)bpv[c];
        out[b * 2 + c] = (float)acc;
    }
}

extern "C" void kernel_launch(void* const* d_in, const int* in_sizes, int n_in,
                              void* d_out, int out_size, void* d_ws, size_t ws_size,
                              hipStream_t stream) {
    const int* X = (const int*)d_in[0];
    const float* embed = (const float*)d_in[1];
    const float* k1 = (const float*)d_in[2];
    const float* b1 = (const float*)d_in[3];
    const float* k2 = (const float*)d_in[4];
    const float* b2 = (const float*)d_in[5];
    const float* w1 = (const float*)d_in[6];
    const float* bw1 = (const float*)d_in[7];
    const float* w2 = (const float*)d_in[8];
    const float* bw2 = (const float*)d_in[9];
    const float* wpm = (const float*)d_in[10];
    const float* bpv = (const float*)d_in[11];

    // zero h/c state buffers + barrier counter (captured into the graph,
    // so every replay starts from a clean deterministic state)
    hipMemsetAsync(d_ws, 0, 1048576, stream);
    hipMemsetAsync((char*)d_ws + OFF_CNT, 0, 256, stream);

    rnn_all<<<NBLK, NTHR, 0, stream>>>(X, embed, k1, b1, k2, b2, w1, bw1,
                                       w2, bw2, wpm, bpv,
                                       (float*)d_out, (char*)d_ws);
}